// Round 2
// baseline (641.743 us; speedup 1.0000x reference)
//
#include <hip/hip_runtime.h>

#define NNODES 50000
#define NEDGES 800000
#define F_IN   128
#define HID    256
#define NOUT   40

// ---------------- CSR build ----------------

__global__ __launch_bounds__(256) void k_degree(const int* __restrict__ dst,
                                                int* __restrict__ count) {
  int e = blockIdx.x * 256 + threadIdx.x;
  if (e < NEDGES) atomicAdd(&count[dst[e]], 1);
}

__global__ __launch_bounds__(256) void k_dinv(const int* __restrict__ count,
                                              float* __restrict__ dinv) {
  int i = blockIdx.x * 256 + threadIdx.x;
  if (i < NNODES) dinv[i] = rsqrtf((float)(count[i] + 1));  // +1 self-loop
}

__global__ __launch_bounds__(1024) void k_scan(const int* __restrict__ count,
                                               int* __restrict__ rowstart) {
  __shared__ int part[1024];
  int t = threadIdx.x;
  const int CH = (NNODES + 1023) / 1024;  // 49
  int beg = t * CH, end = min(beg + CH, NNODES);
  int s = 0;
  for (int i = beg; i < end; i++) s += count[i];
  part[t] = s;
  __syncthreads();
  for (int off = 1; off < 1024; off <<= 1) {
    int v = (t >= off) ? part[t - off] : 0;
    __syncthreads();
    part[t] += v;
    __syncthreads();
  }
  int run = part[t] - s;  // exclusive prefix of this thread's chunk
  for (int i = beg; i < end; i++) { rowstart[i] = run; run += count[i]; }
  if (t == 1023) rowstart[NNODES] = part[1023];
}

__global__ __launch_bounds__(256) void k_scatter(const int* __restrict__ src,
                                                 const int* __restrict__ dst,
                                                 const int* __restrict__ rowstart,
                                                 int* __restrict__ cursor,
                                                 int* __restrict__ csr) {
  int e = blockIdx.x * 256 + threadIdx.x;
  if (e >= NEDGES) return;
  int d = dst[e];
  int p = rowstart[d] + atomicAdd(&cursor[d], 1);
  csr[p] = src[e];
}

// ---------------- gather-based normalized aggregation ----------------
// One wave per dst node; lane holds F/64 contiguous features.
// Unrolled x4: 4 independent row gathers in flight per wave (latency fix).
// Y[i] = dinv[i]^2 * X[i] + sum_{edges s->i} dinv[s]*dinv[i]*X[s]

template <int F>
__global__ __launch_bounds__(256) void k_agg(const float* __restrict__ X,
                                             const int* __restrict__ rowstart,
                                             const int* __restrict__ csr,
                                             const float* __restrict__ dinv,
                                             float* __restrict__ Y) {
  constexpr int V = F / 64;  // 2 or 4 floats per lane
  int wave = threadIdx.x >> 6, lane = threadIdx.x & 63;
  int node = blockIdx.x * 4 + wave;
  if (node >= NNODES) return;
  float di = dinv[node];
  float acc[V];
  {
    const float* p = X + (size_t)node * F + lane * V;
    if constexpr (V == 4) {
      float4 v = *reinterpret_cast<const float4*>(p);
      acc[0] = v.x * di * di; acc[1] = v.y * di * di;
      acc[2] = v.z * di * di; acc[3] = v.w * di * di;
    } else {
      float2 v = *reinterpret_cast<const float2*>(p);
      acc[0] = v.x * di * di; acc[1] = v.y * di * di;
    }
  }
  int e = rowstart[node], end = rowstart[node + 1];
  for (; e + 4 <= end; e += 4) {
    int s0 = csr[e + 0], s1 = csr[e + 1], s2 = csr[e + 2], s3 = csr[e + 3];
    float w0 = dinv[s0] * di, w1 = dinv[s1] * di;
    float w2 = dinv[s2] * di, w3 = dinv[s3] * di;
    if constexpr (V == 4) {
      float4 r0 = *reinterpret_cast<const float4*>(X + (size_t)s0 * F + lane * 4);
      float4 r1 = *reinterpret_cast<const float4*>(X + (size_t)s1 * F + lane * 4);
      float4 r2 = *reinterpret_cast<const float4*>(X + (size_t)s2 * F + lane * 4);
      float4 r3 = *reinterpret_cast<const float4*>(X + (size_t)s3 * F + lane * 4);
      acc[0] = fmaf(r0.x, w0, acc[0]); acc[1] = fmaf(r0.y, w0, acc[1]);
      acc[2] = fmaf(r0.z, w0, acc[2]); acc[3] = fmaf(r0.w, w0, acc[3]);
      acc[0] = fmaf(r1.x, w1, acc[0]); acc[1] = fmaf(r1.y, w1, acc[1]);
      acc[2] = fmaf(r1.z, w1, acc[2]); acc[3] = fmaf(r1.w, w1, acc[3]);
      acc[0] = fmaf(r2.x, w2, acc[0]); acc[1] = fmaf(r2.y, w2, acc[1]);
      acc[2] = fmaf(r2.z, w2, acc[2]); acc[3] = fmaf(r2.w, w2, acc[3]);
      acc[0] = fmaf(r3.x, w3, acc[0]); acc[1] = fmaf(r3.y, w3, acc[1]);
      acc[2] = fmaf(r3.z, w3, acc[2]); acc[3] = fmaf(r3.w, w3, acc[3]);
    } else {
      float2 r0 = *reinterpret_cast<const float2*>(X + (size_t)s0 * F + lane * 2);
      float2 r1 = *reinterpret_cast<const float2*>(X + (size_t)s1 * F + lane * 2);
      float2 r2 = *reinterpret_cast<const float2*>(X + (size_t)s2 * F + lane * 2);
      float2 r3 = *reinterpret_cast<const float2*>(X + (size_t)s3 * F + lane * 2);
      acc[0] = fmaf(r0.x, w0, acc[0]); acc[1] = fmaf(r0.y, w0, acc[1]);
      acc[0] = fmaf(r1.x, w1, acc[0]); acc[1] = fmaf(r1.y, w1, acc[1]);
      acc[0] = fmaf(r2.x, w2, acc[0]); acc[1] = fmaf(r2.y, w2, acc[1]);
      acc[0] = fmaf(r3.x, w3, acc[0]); acc[1] = fmaf(r3.y, w3, acc[1]);
    }
  }
  for (; e < end; ++e) {
    int s = csr[e];
    float w = dinv[s] * di;
    const float* p = X + (size_t)s * F + lane * V;
    if constexpr (V == 4) {
      float4 v = *reinterpret_cast<const float4*>(p);
      acc[0] = fmaf(v.x, w, acc[0]); acc[1] = fmaf(v.y, w, acc[1]);
      acc[2] = fmaf(v.z, w, acc[2]); acc[3] = fmaf(v.w, w, acc[3]);
    } else {
      float2 v = *reinterpret_cast<const float2*>(p);
      acc[0] = fmaf(v.x, w, acc[0]); acc[1] = fmaf(v.y, w, acc[1]);
    }
  }
  float* q = Y + (size_t)node * F + lane * V;
  if constexpr (V == 4) {
    float4 v; v.x = acc[0]; v.y = acc[1]; v.z = acc[2]; v.w = acc[3];
    *reinterpret_cast<float4*>(q) = v;
  } else {
    float2 v; v.x = acc[0]; v.y = acc[1];
    *reinterpret_cast<float2*>(q) = v;
  }
}

// ---------------- fp32 tiled GEMM: C = A[MxK] @ B[KxNc] + bias, opt ReLU ----
// BM=BN=128, BK=16, 256 threads, 8x8 micro-tile (rows {ty*4+i, 64+ty*4+i},
// cols {tx*4+j, 64+tx*4+j}). As padded [16][132] for conflict-free transpose
// stores; compute reads are broadcast (A) / <=2-way (B).

template <bool RELU>
__global__ __launch_bounds__(256) void k_gemm128(const float* __restrict__ A,
                                                 const float* __restrict__ B,
                                                 const float* __restrict__ bias,
                                                 float* __restrict__ C,
                                                 int M, int Nc, int K) {
  __shared__ float As[16][132];
  __shared__ float Bs[16][128];
  int tid = threadIdx.x;
  int bm = blockIdx.x * 128;
  int bn = blockIdx.y * 128;
  int tx = tid & 15, ty = tid >> 4;
  float acc[8][8] = {};

  for (int kt = 0; kt < K; kt += 16) {
    // stage A: 128 rows x 16 k = 512 float4, transposed to As[k][m]
#pragma unroll
    for (int it = 0; it < 2; it++) {
      int i = tid + it * 256;
      int row = i >> 2, q = (i & 3) * 4;
      int gm = bm + row;
      float4 v = {0.f, 0.f, 0.f, 0.f};
      if (gm < M) v = *reinterpret_cast<const float4*>(A + (size_t)gm * K + kt + q);
      As[q + 0][row] = v.x; As[q + 1][row] = v.y;
      As[q + 2][row] = v.z; As[q + 3][row] = v.w;
    }
    // stage B: 16 k-rows x 128 cols = 512 float4
#pragma unroll
    for (int it = 0; it < 2; it++) {
      int i = tid + it * 256;
      int kr = i >> 5, nc = (i & 31) * 4;
      int gn = bn + nc;
      float4 v = {0.f, 0.f, 0.f, 0.f};
      if (gn + 3 < Nc) {
        v = *reinterpret_cast<const float4*>(B + (size_t)(kt + kr) * Nc + gn);
      } else if (gn < Nc) {
        float t0[4] = {0.f, 0.f, 0.f, 0.f};
        for (int j = 0; j < 4; j++)
          if (gn + j < Nc) t0[j] = B[(size_t)(kt + kr) * Nc + gn + j];
        v.x = t0[0]; v.y = t0[1]; v.z = t0[2]; v.w = t0[3];
      }
      *reinterpret_cast<float4*>(&Bs[kr][nc]) = v;
    }
    __syncthreads();
#pragma unroll
    for (int k = 0; k < 16; k++) {
      float a[8], b[8];
      *reinterpret_cast<float4*>(&a[0]) = *reinterpret_cast<const float4*>(&As[k][ty * 4]);
      *reinterpret_cast<float4*>(&a[4]) = *reinterpret_cast<const float4*>(&As[k][64 + ty * 4]);
      *reinterpret_cast<float4*>(&b[0]) = *reinterpret_cast<const float4*>(&Bs[k][tx * 4]);
      *reinterpret_cast<float4*>(&b[4]) = *reinterpret_cast<const float4*>(&Bs[k][64 + tx * 4]);
#pragma unroll
      for (int i = 0; i < 8; i++)
#pragma unroll
        for (int j = 0; j < 8; j++) acc[i][j] = fmaf(a[i], b[j], acc[i][j]);
    }
    __syncthreads();
  }

#pragma unroll
  for (int i = 0; i < 8; i++) {
    int gm = bm + ((i < 4) ? (ty * 4 + i) : (64 + ty * 4 + (i - 4)));
    if (gm >= M) continue;
    int gn0 = bn + tx * 4;
    int gn1 = bn + 64 + tx * 4;
    if (gn0 + 3 < Nc) {
      float4 v;
      v.x = acc[i][0] + bias[gn0 + 0]; v.y = acc[i][1] + bias[gn0 + 1];
      v.z = acc[i][2] + bias[gn0 + 2]; v.w = acc[i][3] + bias[gn0 + 3];
      if (RELU) { v.x = fmaxf(v.x, 0.f); v.y = fmaxf(v.y, 0.f);
                  v.z = fmaxf(v.z, 0.f); v.w = fmaxf(v.w, 0.f); }
      *reinterpret_cast<float4*>(C + (size_t)gm * Nc + gn0) = v;
    } else {
      for (int j = 0; j < 4; j++)
        if (gn0 + j < Nc) {
          float v = acc[i][j] + bias[gn0 + j];
          if (RELU) v = fmaxf(v, 0.f);
          C[(size_t)gm * Nc + gn0 + j] = v;
        }
    }
    if (gn1 + 3 < Nc) {
      float4 v;
      v.x = acc[i][4] + bias[gn1 + 0]; v.y = acc[i][5] + bias[gn1 + 1];
      v.z = acc[i][6] + bias[gn1 + 2]; v.w = acc[i][7] + bias[gn1 + 3];
      if (RELU) { v.x = fmaxf(v.x, 0.f); v.y = fmaxf(v.y, 0.f);
                  v.z = fmaxf(v.z, 0.f); v.w = fmaxf(v.w, 0.f); }
      *reinterpret_cast<float4*>(C + (size_t)gm * Nc + gn1) = v;
    } else {
      for (int j = 0; j < 4; j++)
        if (gn1 + j < Nc) {
          float v = acc[i][4 + j] + bias[gn1 + j];
          if (RELU) v = fmaxf(v, 0.f);
          C[(size_t)gm * Nc + gn1 + j] = v;
        }
    }
  }
}

// ---------------- launch ----------------

extern "C" void kernel_launch(void* const* d_in, const int* in_sizes, int n_in,
                              void* d_out, int out_size, void* d_ws, size_t ws_size,
                              hipStream_t stream) {
  (void)in_sizes; (void)n_in; (void)out_size; (void)ws_size;
  const float* x  = (const float*)d_in[0];
  const float* W1 = (const float*)d_in[1];
  const float* b1 = (const float*)d_in[2];
  const float* W2 = (const float*)d_in[3];
  const float* b2 = (const float*)d_in[4];
  const float* Wc = (const float*)d_in[5];
  const float* bc = (const float*)d_in[6];
  const int* edge = (const int*)d_in[7];
  const int* srcE = edge;           // edge_index[0]
  const int* dstE = edge + NEDGES;  // edge_index[1]
  float* out = (float*)d_out;

  char* ws = (char*)d_ws;
  int*   count    = (int*)(ws + 0);                    // N ints
  int*   cursor   = (int*)(ws + 200000);               // N ints
  int*   rowstart = (int*)(ws + 400000);               // N+1 ints
  float* dinv     = (float*)(ws + 600064);             // N floats
  int*   csr      = (int*)(ws + 800128);               // E ints
  float* aggx     = (float*)(ws + 4000256);            // N*128 f32
  float* h1       = (float*)(ws + 29600256);           // N*256 f32 (reused for h2)
  float* aggh     = (float*)(ws + 80800256);           // N*256 f32
  // total ~132 MB

  hipMemsetAsync(ws, 0, 400000, stream);  // zero count + cursor

  k_degree<<<(NEDGES + 255) / 256, 256, 0, stream>>>(dstE, count);
  k_dinv<<<(NNODES + 255) / 256, 256, 0, stream>>>(count, dinv);
  k_scan<<<1, 1024, 0, stream>>>(count, rowstart);
  k_scatter<<<(NEDGES + 255) / 256, 256, 0, stream>>>(srcE, dstE, rowstart, cursor, csr);

  // layer 1: agg on 128-dim input, then GEMM+bias+ReLU
  k_agg<F_IN><<<(NNODES + 3) / 4, 256, 0, stream>>>(x, rowstart, csr, dinv, aggx);
  {
    dim3 grid((NNODES + 127) / 128, (HID + 127) / 128);
    k_gemm128<true><<<grid, 256, 0, stream>>>(aggx, W1, b1, h1, NNODES, HID, F_IN);
  }
  // layer 2: agg on 256-dim hidden, then GEMM+bias+ReLU (h2 overwrites h1 buffer)
  k_agg<HID><<<(NNODES + 3) / 4, 256, 0, stream>>>(h1, rowstart, csr, dinv, aggh);
  float* h2 = h1;
  {
    dim3 grid((NNODES + 127) / 128, (HID + 127) / 128);
    k_gemm128<true><<<grid, 256, 0, stream>>>(aggh, W2, b2, h2, NNODES, HID, HID);
  }
  // classifier (Nc=40: B-staging and C-store guards handle the tail)
  {
    dim3 grid((NNODES + 127) / 128, (NOUT + 127) / 128);
    k_gemm128<false><<<grid, 256, 0, stream>>>(h2, Wc, bc, out, NNODES, NOUT, HID);
  }
}

// Round 3
// 480.101 us; speedup vs baseline: 1.3367x; 1.3367x over previous
//
#include <hip/hip_runtime.h>

#define NNODES 50000
#define NEDGES 800000
#define F_IN   128
#define HID    256
#define NOUT   40
#define NOUT_PAD 128

typedef __attribute__((ext_vector_type(8))) short bf16x8;
typedef __attribute__((ext_vector_type(4))) float f32x4;

__device__ __forceinline__ unsigned short f2bf(float f) {
  unsigned u = __builtin_bit_cast(unsigned, f);
  u += 0x7fffu + ((u >> 16) & 1u);
  return (unsigned short)(u >> 16);
}
__device__ __forceinline__ float bf2f(unsigned short h) {
  return __builtin_bit_cast(float, (unsigned)h << 16);
}

// ---------------- CSR build ----------------

__global__ __launch_bounds__(256) void k_degree(const int* __restrict__ dst,
                                                int* __restrict__ count) {
  int e = blockIdx.x * 256 + threadIdx.x;
  if (e < NEDGES) atomicAdd(&count[dst[e]], 1);
}

__global__ __launch_bounds__(256) void k_dinv(const int* __restrict__ count,
                                              float* __restrict__ dinv) {
  int i = blockIdx.x * 256 + threadIdx.x;
  if (i < NNODES) dinv[i] = rsqrtf((float)(count[i] + 1));  // +1 self-loop
}

__global__ __launch_bounds__(1024) void k_scan(const int* __restrict__ count,
                                               int* __restrict__ rowstart) {
  __shared__ int part[1024];
  int t = threadIdx.x;
  const int CH = (NNODES + 1023) / 1024;
  int beg = t * CH, end = min(beg + CH, NNODES);
  int s = 0;
  for (int i = beg; i < end; i++) s += count[i];
  part[t] = s;
  __syncthreads();
  for (int off = 1; off < 1024; off <<= 1) {
    int v = (t >= off) ? part[t - off] : 0;
    __syncthreads();
    part[t] += v;
    __syncthreads();
  }
  int run = part[t] - s;
  for (int i = beg; i < end; i++) { rowstart[i] = run; run += count[i]; }
  if (t == 1023) rowstart[NNODES] = part[1023];
}

__global__ __launch_bounds__(256) void k_scatter(const int* __restrict__ src,
                                                 const int* __restrict__ dst,
                                                 const int* __restrict__ rowstart,
                                                 int* __restrict__ cursor,
                                                 int* __restrict__ csr) {
  int e = blockIdx.x * 256 + threadIdx.x;
  if (e >= NEDGES) return;
  int d = dst[e];
  int p = rowstart[d] + atomicAdd(&cursor[d], 1);
  csr[p] = src[e];
}

// ---------------- weight transpose + hi/lo bf16 split ----------------
// Th/Tl are [Npad][K] row-major = W^T; rows >= Nvalid zero-filled.

__global__ __launch_bounds__(256) void k_prep(const float* __restrict__ W, int K, int N,
                                              int Nvalid, int Npad,
                                              unsigned short* __restrict__ Th,
                                              unsigned short* __restrict__ Tl) {
  int idx = blockIdx.x * 256 + threadIdx.x;
  if (idx >= Npad * K) return;
  int n = idx / K, k = idx - n * K;
  float v = (n < Nvalid) ? W[(size_t)k * N + n] : 0.f;
  unsigned short hi = f2bf(v);
  Th[idx] = hi;
  Tl[idx] = f2bf(v - bf2f(hi));
}

// ---------------- agg layer 1: fp32 gather (F=128), split bf16 output -------
// Y[i] = dinv[i]^2 * X[i] + sum_{s->i} dinv[s]*dinv[i]*X[s]

__global__ __launch_bounds__(256) void k_agg1(const float* __restrict__ X,
                                              const int* __restrict__ rowstart,
                                              const int* __restrict__ csr,
                                              const float* __restrict__ dinv,
                                              unsigned int* __restrict__ Yhi,
                                              unsigned int* __restrict__ Ylo) {
  int wave = threadIdx.x >> 6, lane = threadIdx.x & 63;
  int node = blockIdx.x * 4 + wave;
  if (node >= NNODES) return;
  float di = dinv[node];
  float2 self = *reinterpret_cast<const float2*>(X + (size_t)node * F_IN + lane * 2);
  float a0 = self.x * di * di, a1 = self.y * di * di;
  int e = rowstart[node], end = rowstart[node + 1];
  for (; e + 4 <= end; e += 4) {
    int s0 = csr[e], s1 = csr[e + 1], s2 = csr[e + 2], s3 = csr[e + 3];
    float w0 = dinv[s0] * di, w1 = dinv[s1] * di;
    float w2 = dinv[s2] * di, w3 = dinv[s3] * di;
    float2 r0 = *reinterpret_cast<const float2*>(X + (size_t)s0 * F_IN + lane * 2);
    float2 r1 = *reinterpret_cast<const float2*>(X + (size_t)s1 * F_IN + lane * 2);
    float2 r2 = *reinterpret_cast<const float2*>(X + (size_t)s2 * F_IN + lane * 2);
    float2 r3 = *reinterpret_cast<const float2*>(X + (size_t)s3 * F_IN + lane * 2);
    a0 = fmaf(r0.x, w0, a0); a1 = fmaf(r0.y, w0, a1);
    a0 = fmaf(r1.x, w1, a0); a1 = fmaf(r1.y, w1, a1);
    a0 = fmaf(r2.x, w2, a0); a1 = fmaf(r2.y, w2, a1);
    a0 = fmaf(r3.x, w3, a0); a1 = fmaf(r3.y, w3, a1);
  }
  for (; e < end; ++e) {
    int s = csr[e];
    float w = dinv[s] * di;
    float2 r = *reinterpret_cast<const float2*>(X + (size_t)s * F_IN + lane * 2);
    a0 = fmaf(r.x, w, a0); a1 = fmaf(r.y, w, a1);
  }
  unsigned short h0 = f2bf(a0), h1 = f2bf(a1);
  unsigned short l0 = f2bf(a0 - bf2f(h0)), l1 = f2bf(a1 - bf2f(h1));
  Yhi[(size_t)node * 64 + lane] = (unsigned)h0 | ((unsigned)h1 << 16);
  Ylo[(size_t)node * 64 + lane] = (unsigned)l0 | ((unsigned)l1 << 16);
}

// ---------------- agg layer 2: bf16 gather (F=256), split bf16 output -------

__global__ __launch_bounds__(256) void k_agg2(const unsigned short* __restrict__ H,
                                              const int* __restrict__ rowstart,
                                              const int* __restrict__ csr,
                                              const float* __restrict__ dinv,
                                              uint2* __restrict__ Yhi,
                                              uint2* __restrict__ Ylo) {
  int wave = threadIdx.x >> 6, lane = threadIdx.x & 63;
  int node = blockIdx.x * 4 + wave;
  if (node >= NNODES) return;
  float di = dinv[node];
  float a0, a1, a2, a3;
  {
    ushort4 v = *reinterpret_cast<const ushort4*>(H + (size_t)node * HID + lane * 4);
    a0 = bf2f(v.x) * di * di; a1 = bf2f(v.y) * di * di;
    a2 = bf2f(v.z) * di * di; a3 = bf2f(v.w) * di * di;
  }
  int e = rowstart[node], end = rowstart[node + 1];
  for (; e + 4 <= end; e += 4) {
    int s0 = csr[e], s1 = csr[e + 1], s2 = csr[e + 2], s3 = csr[e + 3];
    float w0 = dinv[s0] * di, w1 = dinv[s1] * di;
    float w2 = dinv[s2] * di, w3 = dinv[s3] * di;
    ushort4 r0 = *reinterpret_cast<const ushort4*>(H + (size_t)s0 * HID + lane * 4);
    ushort4 r1 = *reinterpret_cast<const ushort4*>(H + (size_t)s1 * HID + lane * 4);
    ushort4 r2 = *reinterpret_cast<const ushort4*>(H + (size_t)s2 * HID + lane * 4);
    ushort4 r3 = *reinterpret_cast<const ushort4*>(H + (size_t)s3 * HID + lane * 4);
    a0 = fmaf(bf2f(r0.x), w0, a0); a1 = fmaf(bf2f(r0.y), w0, a1);
    a2 = fmaf(bf2f(r0.z), w0, a2); a3 = fmaf(bf2f(r0.w), w0, a3);
    a0 = fmaf(bf2f(r1.x), w1, a0); a1 = fmaf(bf2f(r1.y), w1, a1);
    a2 = fmaf(bf2f(r1.z), w1, a2); a3 = fmaf(bf2f(r1.w), w1, a3);
    a0 = fmaf(bf2f(r2.x), w2, a0); a1 = fmaf(bf2f(r2.y), w2, a1);
    a2 = fmaf(bf2f(r2.z), w2, a2); a3 = fmaf(bf2f(r2.w), w2, a3);
    a0 = fmaf(bf2f(r3.x), w3, a0); a1 = fmaf(bf2f(r3.y), w3, a1);
    a2 = fmaf(bf2f(r3.z), w3, a2); a3 = fmaf(bf2f(r3.w), w3, a3);
  }
  for (; e < end; ++e) {
    int s = csr[e];
    float w = dinv[s] * di;
    ushort4 r = *reinterpret_cast<const ushort4*>(H + (size_t)s * HID + lane * 4);
    a0 = fmaf(bf2f(r.x), w, a0); a1 = fmaf(bf2f(r.y), w, a1);
    a2 = fmaf(bf2f(r.z), w, a2); a3 = fmaf(bf2f(r.w), w, a3);
  }
  unsigned short h0 = f2bf(a0), h1 = f2bf(a1), h2 = f2bf(a2), h3 = f2bf(a3);
  unsigned short l0 = f2bf(a0 - bf2f(h0)), l1 = f2bf(a1 - bf2f(h1));
  unsigned short l2 = f2bf(a2 - bf2f(h2)), l3 = f2bf(a3 - bf2f(h3));
  uint2 vh, vl;
  vh.x = (unsigned)h0 | ((unsigned)h1 << 16); vh.y = (unsigned)h2 | ((unsigned)h3 << 16);
  vl.x = (unsigned)l0 | ((unsigned)l1 << 16); vl.y = (unsigned)l2 | ((unsigned)l3 << 16);
  Yhi[(size_t)node * 64 + lane] = vh;
  Ylo[(size_t)node * 64 + lane] = vl;
}

// ---------------- split-bf16 MFMA GEMM ----------------
// C = A[MxK] @ B[KxN] + bias via 3-term bf16 split (fp32-grade accuracy).
// A given as hi/lo bf16 row-major [M][K]; B given as TRANSPOSED hi/lo [Npad][K].
// BM=BN=128, BK=32, 256 threads = 4 waves (2x2), each wave 64x64 out.
// LDS rows padded to 40 bf16 (80 B) -> 2-way bank aliasing (free).
// OMODE: 0 = f32 out, 1 = bf16 out, 2 = split hi/lo out.

template <int RELU, int OMODE>
__global__ __launch_bounds__(256) void k_mgemm(const unsigned short* __restrict__ Ahg,
                                               const unsigned short* __restrict__ Alg,
                                               const unsigned short* __restrict__ Bth,
                                               const unsigned short* __restrict__ Btl,
                                               const float* __restrict__ bias,
                                               void* __restrict__ Cout,
                                               void* __restrict__ Cout2,
                                               int M, int Nc, int K) {
  __shared__ unsigned short Ah[128 * 40], Al[128 * 40], Bh[128 * 40], Bl[128 * 40];
  int tid = threadIdx.x;
  int lane = tid & 63, w = tid >> 6;
  int wr = w >> 1, wc = w & 1;
  int bm = blockIdx.x * 128, bn = blockIdx.y * 128;
  int l15 = lane & 15, kg = lane >> 4;

  f32x4 zero = {0.f, 0.f, 0.f, 0.f};
  f32x4 acc[4][4];
#pragma unroll
  for (int i = 0; i < 4; i++)
#pragma unroll
    for (int j = 0; j < 4; j++) acc[i][j] = zero;

  for (int kt = 0; kt < K; kt += 32) {
#pragma unroll
    for (int it = 0; it < 2; it++) {
      int c = tid + it * 256;        // 0..511
      int row = c >> 2, kq = c & 3;  // 128 rows x 4 16B-chunks
      int ldso = row * 40 + kq * 8;
      // A (guard M, zero-fill)
      {
        int gm = bm + row;
        uint4 vh = {0, 0, 0, 0}, vl = {0, 0, 0, 0};
        if (gm < M) {
          size_t g = (size_t)gm * K + kt + kq * 8;
          vh = *reinterpret_cast<const uint4*>(Ahg + g);
          vl = *reinterpret_cast<const uint4*>(Alg + g);
        }
        *reinterpret_cast<uint4*>(&Ah[ldso]) = vh;
        *reinterpret_cast<uint4*>(&Al[ldso]) = vl;
      }
      // B^T (padded to Npad rows, no guard)
      {
        size_t g = (size_t)(bn + row) * K + kt + kq * 8;
        *reinterpret_cast<uint4*>(&Bh[ldso]) = *reinterpret_cast<const uint4*>(Bth + g);
        *reinterpret_cast<uint4*>(&Bl[ldso]) = *reinterpret_cast<const uint4*>(Btl + g);
      }
    }
    __syncthreads();

    bf16x8 fah[4], fal[4], fbh[4], fbl[4];
#pragma unroll
    for (int f = 0; f < 4; f++) {
      int ra = (wr * 64 + f * 16 + l15) * 40 + kg * 8;
      fah[f] = *reinterpret_cast<const bf16x8*>(&Ah[ra]);
      fal[f] = *reinterpret_cast<const bf16x8*>(&Al[ra]);
      int rb = (wc * 64 + f * 16 + l15) * 40 + kg * 8;
      fbh[f] = *reinterpret_cast<const bf16x8*>(&Bh[rb]);
      fbl[f] = *reinterpret_cast<const bf16x8*>(&Bl[rb]);
    }
#pragma unroll
    for (int i = 0; i < 4; i++)
#pragma unroll
      for (int j = 0; j < 4; j++) {
        acc[i][j] = __builtin_amdgcn_mfma_f32_16x16x32_bf16(fah[i], fbh[j], acc[i][j], 0, 0, 0);
        acc[i][j] = __builtin_amdgcn_mfma_f32_16x16x32_bf16(fah[i], fbl[j], acc[i][j], 0, 0, 0);
        acc[i][j] = __builtin_amdgcn_mfma_f32_16x16x32_bf16(fal[i], fbh[j], acc[i][j], 0, 0, 0);
      }
    __syncthreads();
  }

  // epilogue: D row = (lane>>4)*4 + reg (within 16-row frag), col = lane&15
  int r0 = kg * 4;
#pragma unroll
  for (int i = 0; i < 4; i++) {
    int gmBase = bm + wr * 64 + i * 16 + r0;
#pragma unroll
    for (int r = 0; r < 4; r++) {
      int gm = gmBase + r;
      if (gm >= M) continue;
#pragma unroll
      for (int j = 0; j < 4; j++) {
        int gn = bn + wc * 64 + j * 16 + l15;
        if (gn >= Nc) continue;
        float v = acc[i][j][r] + bias[gn];
        if (RELU) v = fmaxf(v, 0.f);
        size_t o = (size_t)gm * Nc + gn;
        if (OMODE == 0) {
          ((float*)Cout)[o] = v;
        } else if (OMODE == 1) {
          ((unsigned short*)Cout)[o] = f2bf(v);
        } else {
          unsigned short hi = f2bf(v);
          ((unsigned short*)Cout)[o] = hi;
          ((unsigned short*)Cout2)[o] = f2bf(v - bf2f(hi));
        }
      }
    }
  }
}

// ---------------- launch ----------------

extern "C" void kernel_launch(void* const* d_in, const int* in_sizes, int n_in,
                              void* d_out, int out_size, void* d_ws, size_t ws_size,
                              hipStream_t stream) {
  (void)in_sizes; (void)n_in; (void)out_size; (void)ws_size;
  const float* x  = (const float*)d_in[0];
  const float* W1 = (const float*)d_in[1];
  const float* b1 = (const float*)d_in[2];
  const float* W2 = (const float*)d_in[3];
  const float* b2 = (const float*)d_in[4];
  const float* Wc = (const float*)d_in[5];
  const float* bc = (const float*)d_in[6];
  const int* edge = (const int*)d_in[7];
  const int* srcE = edge;
  const int* dstE = edge + NEDGES;
  float* out = (float*)d_out;

  char* ws = (char*)d_ws;
  int*   count    = (int*)(ws + 0);          // 200000 B
  int*   cursor   = (int*)(ws + 200064);     // 200000 B
  int*   rowstart = (int*)(ws + 400128);     // 200004 B
  float* dinv     = (float*)(ws + 600320);   // 200000 B
  int*   csr      = (int*)(ws + 800384);     // 3200000 B
  unsigned short* W1th = (unsigned short*)(ws + 4000512);  // 256x128
  unsigned short* W1tl = (unsigned short*)(ws + 4066048);
  unsigned short* W2th = (unsigned short*)(ws + 4131584);  // 256x256
  unsigned short* W2tl = (unsigned short*)(ws + 4262656);
  unsigned short* Wcth = (unsigned short*)(ws + 4393728);  // 128x256 (padded)
  unsigned short* Wctl = (unsigned short*)(ws + 4459264);
  // feature pools (P1 reused: aggx+h1 then h2)
  char* P1 = ws + 4524800;                   // 51.2 MB
  char* P2 = ws + 55724800;                  // 51.2 MB
  unsigned short* aggx_hi = (unsigned short*)(P1 + 0);         // 50000x128
  unsigned short* aggx_lo = (unsigned short*)(P1 + 12800000);
  unsigned short* h1      = (unsigned short*)(P1 + 25600000);  // 50000x256 bf16
  unsigned short* h2_hi   = (unsigned short*)(P1 + 0);         // 50000x256 (after h1/aggx dead)
  unsigned short* h2_lo   = (unsigned short*)(P1 + 25600000);
  unsigned short* aggh_hi = (unsigned short*)(P2 + 0);         // 50000x256
  unsigned short* aggh_lo = (unsigned short*)(P2 + 25600000);

  hipMemsetAsync(ws, 0, 400128, stream);  // count + cursor

  k_degree<<<(NEDGES + 255) / 256, 256, 0, stream>>>(dstE, count);
  k_dinv<<<(NNODES + 255) / 256, 256, 0, stream>>>(count, dinv);
  k_scan<<<1, 1024, 0, stream>>>(count, rowstart);
  k_scatter<<<(NEDGES + 255) / 256, 256, 0, stream>>>(srcE, dstE, rowstart, cursor, csr);

  // weight prep (transpose + split)
  k_prep<<<(HID * F_IN + 255) / 256, 256, 0, stream>>>(W1, F_IN, HID, HID, HID, W1th, W1tl);
  k_prep<<<(HID * HID + 255) / 256, 256, 0, stream>>>(W2, HID, HID, HID, HID, W2th, W2tl);
  k_prep<<<(NOUT_PAD * HID + 255) / 256, 256, 0, stream>>>(Wc, HID, NOUT, NOUT, NOUT_PAD, Wcth, Wctl);

  // layer 1
  k_agg1<<<(NNODES + 3) / 4, 256, 0, stream>>>(x, rowstart, csr, dinv,
                                               (unsigned int*)aggx_hi, (unsigned int*)aggx_lo);
  {
    dim3 grid((NNODES + 127) / 128, HID / 128);
    k_mgemm<1, 1><<<grid, 256, 0, stream>>>(aggx_hi, aggx_lo, W1th, W1tl, b1,
                                            (void*)h1, nullptr, NNODES, HID, F_IN);
  }
  // layer 2
  k_agg2<<<(NNODES + 3) / 4, 256, 0, stream>>>(h1, rowstart, csr, dinv,
                                               (uint2*)aggh_hi, (uint2*)aggh_lo);
  {
    dim3 grid((NNODES + 127) / 128, HID / 128);
    k_mgemm<1, 2><<<grid, 256, 0, stream>>>(aggh_hi, aggh_lo, W2th, W2tl, b2,
                                            (void*)h2_hi, (void*)h2_lo, NNODES, HID, HID);
  }
  // classifier
  {
    dim3 grid((NNODES + 127) / 128, NOUT_PAD / 128);
    k_mgemm<0, 0><<<grid, 256, 0, stream>>>(h2_hi, h2_lo, Wcth, Wctl, bc,
                                            (void*)out, nullptr, NNODES, NOUT, HID);
  }
}

// Round 4
// 394.736 us; speedup vs baseline: 1.6258x; 1.2163x over previous
//
#include <hip/hip_runtime.h>

#define NNODES 50000
#define NEDGES 800000
#define F_IN   128
#define HID    256
#define NOUT   40
#define NOUT_PAD 128
#define NBLK_SCAN ((NNODES + 255) / 256)  // 196

typedef __attribute__((ext_vector_type(8))) short bf16x8;
typedef __attribute__((ext_vector_type(4))) float f32x4;

__device__ __forceinline__ unsigned short f2bf(float f) {
  unsigned u = __builtin_bit_cast(unsigned, f);
  u += 0x7fffu + ((u >> 16) & 1u);
  return (unsigned short)(u >> 16);
}
__device__ __forceinline__ float bf2f(unsigned short h) {
  return __builtin_bit_cast(float, (unsigned)h << 16);
}
__device__ __forceinline__ unsigned short f2h(float f) {
  return __builtin_bit_cast(unsigned short, (_Float16)f);
}
__device__ __forceinline__ float h2f(unsigned short u) {
  return (float)__builtin_bit_cast(_Float16, u);
}

// ---------------- CSR build ----------------

__global__ __launch_bounds__(256) void k_degree(const int* __restrict__ dst,
                                                int* __restrict__ count) {
  int e = blockIdx.x * 256 + threadIdx.x;
  if (e < NEDGES) atomicAdd(&count[dst[e]], 1);
}

__global__ __launch_bounds__(256) void k_scan1(const int* __restrict__ count,
                                               int* __restrict__ rowstart,
                                               int* __restrict__ bsum,
                                               float* __restrict__ dinv) {
  __shared__ int tmp[256];
  int t = threadIdx.x;
  int i = blockIdx.x * 256 + t;
  int v = (i < NNODES) ? count[i] : 0;
  if (i < NNODES) dinv[i] = rsqrtf((float)(v + 1));  // +1 self-loop
  tmp[t] = v;
  __syncthreads();
  for (int off = 1; off < 256; off <<= 1) {
    int x = (t >= off) ? tmp[t - off] : 0;
    __syncthreads();
    tmp[t] += x;
    __syncthreads();
  }
  if (i < NNODES) rowstart[i] = tmp[t] - v;  // exclusive
  if (t == 255) bsum[blockIdx.x] = tmp[255];
}

__global__ __launch_bounds__(256) void k_scan2(const int* __restrict__ bsum,
                                               int* __restrict__ boff) {
  __shared__ int tmp[256];
  int t = threadIdx.x;
  int v = (t < NBLK_SCAN) ? bsum[t] : 0;
  tmp[t] = v;
  __syncthreads();
  for (int off = 1; off < 256; off <<= 1) {
    int x = (t >= off) ? tmp[t - off] : 0;
    __syncthreads();
    tmp[t] += x;
    __syncthreads();
  }
  if (t < NBLK_SCAN) boff[t] = tmp[t] - v;  // exclusive
}

__global__ __launch_bounds__(256) void k_scan3(int* __restrict__ rowstart,
                                               const int* __restrict__ boff) {
  int i = blockIdx.x * 256 + threadIdx.x;
  if (i < NNODES) rowstart[i] += boff[blockIdx.x];
  if (i == 0) rowstart[NNODES] = NEDGES;
}

__global__ __launch_bounds__(256) void k_scatter(const int* __restrict__ src,
                                                 const int* __restrict__ dst,
                                                 const int* __restrict__ rowstart,
                                                 int* __restrict__ cursor,
                                                 int* __restrict__ csr) {
  int e = blockIdx.x * 256 + threadIdx.x;
  if (e >= NEDGES) return;
  int d = dst[e];
  int p = rowstart[d] + atomicAdd(&cursor[d], 1);
  csr[p] = src[e];
}

// ---------------- x -> fp16 cast ----------------

__global__ __launch_bounds__(256) void k_cast(const float* __restrict__ X,
                                              unsigned short* __restrict__ Xh) {
  int i = blockIdx.x * 256 + threadIdx.x;  // one float4 per thread
  if (i * 4 >= NNODES * F_IN) return;
  float4 v = *reinterpret_cast<const float4*>(X + (size_t)i * 4);
  ushort4 o;
  o.x = f2h(v.x); o.y = f2h(v.y); o.z = f2h(v.z); o.w = f2h(v.w);
  *reinterpret_cast<ushort4*>(Xh + (size_t)i * 4) = o;
}

// ---------------- weight transpose + hi/lo bf16 split ----------------

__global__ __launch_bounds__(256) void k_prep(const float* __restrict__ W, int K, int N,
                                              int Nvalid, int Npad,
                                              unsigned short* __restrict__ Th,
                                              unsigned short* __restrict__ Tl) {
  int idx = blockIdx.x * 256 + threadIdx.x;
  if (idx >= Npad * K) return;
  int n = idx / K, k = idx - n * K;
  float v = (n < Nvalid) ? W[(size_t)k * N + n] : 0.f;
  unsigned short hi = f2bf(v);
  Th[idx] = hi;
  Tl[idx] = f2bf(v - bf2f(hi));
}

// ---------------- agg layer 1: fp16 gather (F=128), split bf16 output -------

__global__ __launch_bounds__(256) void k_agg1(const unsigned short* __restrict__ X,
                                              const int* __restrict__ rowstart,
                                              const int* __restrict__ csr,
                                              const float* __restrict__ dinv,
                                              unsigned int* __restrict__ Yhi,
                                              unsigned int* __restrict__ Ylo) {
  int wave = threadIdx.x >> 6, lane = threadIdx.x & 63;
  int node = blockIdx.x * 4 + wave;
  if (node >= NNODES) return;
  float di = dinv[node];
  float a0, a1;
  {
    ushort2 v = *reinterpret_cast<const ushort2*>(X + (size_t)node * F_IN + lane * 2);
    a0 = h2f(v.x) * di * di; a1 = h2f(v.y) * di * di;
  }
  int e = rowstart[node], end = rowstart[node + 1];
  for (; e + 4 <= end; e += 4) {
    int s0 = csr[e], s1 = csr[e + 1], s2 = csr[e + 2], s3 = csr[e + 3];
    float w0 = dinv[s0] * di, w1 = dinv[s1] * di;
    float w2 = dinv[s2] * di, w3 = dinv[s3] * di;
    ushort2 r0 = *reinterpret_cast<const ushort2*>(X + (size_t)s0 * F_IN + lane * 2);
    ushort2 r1 = *reinterpret_cast<const ushort2*>(X + (size_t)s1 * F_IN + lane * 2);
    ushort2 r2 = *reinterpret_cast<const ushort2*>(X + (size_t)s2 * F_IN + lane * 2);
    ushort2 r3 = *reinterpret_cast<const ushort2*>(X + (size_t)s3 * F_IN + lane * 2);
    a0 = fmaf(h2f(r0.x), w0, a0); a1 = fmaf(h2f(r0.y), w0, a1);
    a0 = fmaf(h2f(r1.x), w1, a0); a1 = fmaf(h2f(r1.y), w1, a1);
    a0 = fmaf(h2f(r2.x), w2, a0); a1 = fmaf(h2f(r2.y), w2, a1);
    a0 = fmaf(h2f(r3.x), w3, a0); a1 = fmaf(h2f(r3.y), w3, a1);
  }
  for (; e < end; ++e) {
    int s = csr[e];
    float w = dinv[s] * di;
    ushort2 r = *reinterpret_cast<const ushort2*>(X + (size_t)s * F_IN + lane * 2);
    a0 = fmaf(h2f(r.x), w, a0); a1 = fmaf(h2f(r.y), w, a1);
  }
  unsigned short h0 = f2bf(a0), h1 = f2bf(a1);
  unsigned short l0 = f2bf(a0 - bf2f(h0)), l1 = f2bf(a1 - bf2f(h1));
  Yhi[(size_t)node * 64 + lane] = (unsigned)h0 | ((unsigned)h1 << 16);
  Ylo[(size_t)node * 64 + lane] = (unsigned)l0 | ((unsigned)l1 << 16);
}

// ---------------- agg layer 2: fp16 gather (F=256), split bf16 output -------

__global__ __launch_bounds__(256) void k_agg2(const unsigned short* __restrict__ H,
                                              const int* __restrict__ rowstart,
                                              const int* __restrict__ csr,
                                              const float* __restrict__ dinv,
                                              uint2* __restrict__ Yhi,
                                              uint2* __restrict__ Ylo) {
  int wave = threadIdx.x >> 6, lane = threadIdx.x & 63;
  int node = blockIdx.x * 4 + wave;
  if (node >= NNODES) return;
  float di = dinv[node];
  float a0, a1, a2, a3;
  {
    ushort4 v = *reinterpret_cast<const ushort4*>(H + (size_t)node * HID + lane * 4);
    a0 = h2f(v.x) * di * di; a1 = h2f(v.y) * di * di;
    a2 = h2f(v.z) * di * di; a3 = h2f(v.w) * di * di;
  }
  int e = rowstart[node], end = rowstart[node + 1];
  for (; e + 4 <= end; e += 4) {
    int s0 = csr[e], s1 = csr[e + 1], s2 = csr[e + 2], s3 = csr[e + 3];
    float w0 = dinv[s0] * di, w1 = dinv[s1] * di;
    float w2 = dinv[s2] * di, w3 = dinv[s3] * di;
    ushort4 r0 = *reinterpret_cast<const ushort4*>(H + (size_t)s0 * HID + lane * 4);
    ushort4 r1 = *reinterpret_cast<const ushort4*>(H + (size_t)s1 * HID + lane * 4);
    ushort4 r2 = *reinterpret_cast<const ushort4*>(H + (size_t)s2 * HID + lane * 4);
    ushort4 r3 = *reinterpret_cast<const ushort4*>(H + (size_t)s3 * HID + lane * 4);
    a0 = fmaf(h2f(r0.x), w0, a0); a1 = fmaf(h2f(r0.y), w0, a1);
    a2 = fmaf(h2f(r0.z), w0, a2); a3 = fmaf(h2f(r0.w), w0, a3);
    a0 = fmaf(h2f(r1.x), w1, a0); a1 = fmaf(h2f(r1.y), w1, a1);
    a2 = fmaf(h2f(r1.z), w1, a2); a3 = fmaf(h2f(r1.w), w1, a3);
    a0 = fmaf(h2f(r2.x), w2, a0); a1 = fmaf(h2f(r2.y), w2, a1);
    a2 = fmaf(h2f(r2.z), w2, a2); a3 = fmaf(h2f(r2.w), w2, a3);
    a0 = fmaf(h2f(r3.x), w3, a0); a1 = fmaf(h2f(r3.y), w3, a1);
    a2 = fmaf(h2f(r3.z), w3, a2); a3 = fmaf(h2f(r3.w), w3, a3);
  }
  for (; e < end; ++e) {
    int s = csr[e];
    float w = dinv[s] * di;
    ushort4 r = *reinterpret_cast<const ushort4*>(H + (size_t)s * HID + lane * 4);
    a0 = fmaf(h2f(r.x), w, a0); a1 = fmaf(h2f(r.y), w, a1);
    a2 = fmaf(h2f(r.z), w, a2); a3 = fmaf(h2f(r.w), w, a3);
  }
  unsigned short h0 = f2bf(a0), h1 = f2bf(a1), h2 = f2bf(a2), h3 = f2bf(a3);
  unsigned short l0 = f2bf(a0 - bf2f(h0)), l1 = f2bf(a1 - bf2f(h1));
  unsigned short l2 = f2bf(a2 - bf2f(h2)), l3 = f2bf(a3 - bf2f(h3));
  uint2 vh, vl;
  vh.x = (unsigned)h0 | ((unsigned)h1 << 16); vh.y = (unsigned)h2 | ((unsigned)h3 << 16);
  vl.x = (unsigned)l0 | ((unsigned)l1 << 16); vl.y = (unsigned)l2 | ((unsigned)l3 << 16);
  Yhi[(size_t)node * 64 + lane] = vh;
  Ylo[(size_t)node * 64 + lane] = vl;
}

// ---------------- split-bf16 MFMA GEMM ----------------
// OMODE: 0 = f32 out, 1 = fp16 out, 2 = split bf16 hi/lo out.

template <int RELU, int OMODE>
__global__ __launch_bounds__(256) void k_mgemm(const unsigned short* __restrict__ Ahg,
                                               const unsigned short* __restrict__ Alg,
                                               const unsigned short* __restrict__ Bth,
                                               const unsigned short* __restrict__ Btl,
                                               const float* __restrict__ bias,
                                               void* __restrict__ Cout,
                                               void* __restrict__ Cout2,
                                               int M, int Nc, int K) {
  __shared__ unsigned short Ah[128 * 40], Al[128 * 40], Bh[128 * 40], Bl[128 * 40];
  int tid = threadIdx.x;
  int lane = tid & 63, w = tid >> 6;
  int wr = w >> 1, wc = w & 1;
  int bm = blockIdx.x * 128, bn = blockIdx.y * 128;
  int l15 = lane & 15, kg = lane >> 4;

  f32x4 zero = {0.f, 0.f, 0.f, 0.f};
  f32x4 acc[4][4];
#pragma unroll
  for (int i = 0; i < 4; i++)
#pragma unroll
    for (int j = 0; j < 4; j++) acc[i][j] = zero;

  for (int kt = 0; kt < K; kt += 32) {
#pragma unroll
    for (int it = 0; it < 2; it++) {
      int c = tid + it * 256;
      int row = c >> 2, kq = c & 3;
      int ldso = row * 40 + kq * 8;
      {
        int gm = bm + row;
        uint4 vh = {0, 0, 0, 0}, vl = {0, 0, 0, 0};
        if (gm < M) {
          size_t g = (size_t)gm * K + kt + kq * 8;
          vh = *reinterpret_cast<const uint4*>(Ahg + g);
          vl = *reinterpret_cast<const uint4*>(Alg + g);
        }
        *reinterpret_cast<uint4*>(&Ah[ldso]) = vh;
        *reinterpret_cast<uint4*>(&Al[ldso]) = vl;
      }
      {
        size_t g = (size_t)(bn + row) * K + kt + kq * 8;
        *reinterpret_cast<uint4*>(&Bh[ldso]) = *reinterpret_cast<const uint4*>(Bth + g);
        *reinterpret_cast<uint4*>(&Bl[ldso]) = *reinterpret_cast<const uint4*>(Btl + g);
      }
    }
    __syncthreads();

    bf16x8 fah[4], fal[4], fbh[4], fbl[4];
#pragma unroll
    for (int f = 0; f < 4; f++) {
      int ra = (wr * 64 + f * 16 + l15) * 40 + kg * 8;
      fah[f] = *reinterpret_cast<const bf16x8*>(&Ah[ra]);
      fal[f] = *reinterpret_cast<const bf16x8*>(&Al[ra]);
      int rb = (wc * 64 + f * 16 + l15) * 40 + kg * 8;
      fbh[f] = *reinterpret_cast<const bf16x8*>(&Bh[rb]);
      fbl[f] = *reinterpret_cast<const bf16x8*>(&Bl[rb]);
    }
#pragma unroll
    for (int i = 0; i < 4; i++)
#pragma unroll
      for (int j = 0; j < 4; j++) {
        acc[i][j] = __builtin_amdgcn_mfma_f32_16x16x32_bf16(fah[i], fbh[j], acc[i][j], 0, 0, 0);
        acc[i][j] = __builtin_amdgcn_mfma_f32_16x16x32_bf16(fah[i], fbl[j], acc[i][j], 0, 0, 0);
        acc[i][j] = __builtin_amdgcn_mfma_f32_16x16x32_bf16(fal[i], fbh[j], acc[i][j], 0, 0, 0);
      }
    __syncthreads();
  }

  int r0 = kg * 4;
#pragma unroll
  for (int i = 0; i < 4; i++) {
    int gmBase = bm + wr * 64 + i * 16 + r0;
#pragma unroll
    for (int r = 0; r < 4; r++) {
      int gm = gmBase + r;
      if (gm >= M) continue;
#pragma unroll
      for (int j = 0; j < 4; j++) {
        int gn = bn + wc * 64 + j * 16 + l15;
        if (gn >= Nc) continue;
        float v = acc[i][j][r] + bias[gn];
        if (RELU) v = fmaxf(v, 0.f);
        size_t o = (size_t)gm * Nc + gn;
        if (OMODE == 0) {
          ((float*)Cout)[o] = v;
        } else if (OMODE == 1) {
          ((unsigned short*)Cout)[o] = f2h(v);
        } else {
          unsigned short hi = f2bf(v);
          ((unsigned short*)Cout)[o] = hi;
          ((unsigned short*)Cout2)[o] = f2bf(v - bf2f(hi));
        }
      }
    }
  }
}

// ---------------- launch ----------------

extern "C" void kernel_launch(void* const* d_in, const int* in_sizes, int n_in,
                              void* d_out, int out_size, void* d_ws, size_t ws_size,
                              hipStream_t stream) {
  (void)in_sizes; (void)n_in; (void)out_size; (void)ws_size;
  const float* x  = (const float*)d_in[0];
  const float* W1 = (const float*)d_in[1];
  const float* b1 = (const float*)d_in[2];
  const float* W2 = (const float*)d_in[3];
  const float* b2 = (const float*)d_in[4];
  const float* Wc = (const float*)d_in[5];
  const float* bc = (const float*)d_in[6];
  const int* edge = (const int*)d_in[7];
  const int* srcE = edge;
  const int* dstE = edge + NEDGES;
  float* out = (float*)d_out;

  char* ws = (char*)d_ws;
  int*   count    = (int*)(ws + 0);          // 200000 B
  int*   cursor   = (int*)(ws + 200064);
  int*   rowstart = (int*)(ws + 400128);     // 200004 B
  float* dinv     = (float*)(ws + 600320);
  int*   csr      = (int*)(ws + 800384);     // 3.2 MB
  int*   bsum     = (int*)(ws + 4000512);    // 196 ints
  int*   boff     = (int*)(ws + 4001536);    // 196 ints
  unsigned short* W1th = (unsigned short*)(ws + 4002560);  // 256x128 bf16
  unsigned short* W1tl = (unsigned short*)(ws + 4068096);
  unsigned short* W2th = (unsigned short*)(ws + 4133632);  // 256x256
  unsigned short* W2tl = (unsigned short*)(ws + 4264704);
  unsigned short* Wcth = (unsigned short*)(ws + 4395776);  // 128x256 (padded)
  unsigned short* Wctl = (unsigned short*)(ws + 4461312);
  unsigned short* xh   = (unsigned short*)(ws + 4526848);  // 50000x128 fp16
  char* P1 = ws + 17326848;  // 51.2 MB pool
  char* P2 = ws + 68526848;  // 51.2 MB pool
  unsigned short* aggx_hi = (unsigned short*)(P1 + 0);         // 50000x128 bf16
  unsigned short* aggx_lo = (unsigned short*)(P1 + 12800000);
  unsigned short* h1      = (unsigned short*)(P1 + 25600000);  // 50000x256 fp16
  unsigned short* h2_hi   = (unsigned short*)(P1 + 0);         // reuse after h1/aggx dead
  unsigned short* h2_lo   = (unsigned short*)(P1 + 25600000);
  unsigned short* aggh_hi = (unsigned short*)(P2 + 0);         // 50000x256 bf16
  unsigned short* aggh_lo = (unsigned short*)(P2 + 25600000);

  hipMemsetAsync(ws, 0, 400128, stream);  // count + cursor

  k_cast<<<(NNODES * F_IN / 4 + 255) / 256, 256, 0, stream>>>(x, xh);
  k_degree<<<(NEDGES + 255) / 256, 256, 0, stream>>>(dstE, count);
  k_scan1<<<NBLK_SCAN, 256, 0, stream>>>(count, rowstart, bsum, dinv);
  k_scan2<<<1, 256, 0, stream>>>(bsum, boff);
  k_scan3<<<NBLK_SCAN, 256, 0, stream>>>(rowstart, boff);
  k_scatter<<<(NEDGES + 255) / 256, 256, 0, stream>>>(srcE, dstE, rowstart, cursor, csr);

  k_prep<<<(HID * F_IN + 255) / 256, 256, 0, stream>>>(W1, F_IN, HID, HID, HID, W1th, W1tl);
  k_prep<<<(HID * HID + 255) / 256, 256, 0, stream>>>(W2, HID, HID, HID, HID, W2th, W2tl);
  k_prep<<<(NOUT_PAD * HID + 255) / 256, 256, 0, stream>>>(Wc, HID, NOUT, NOUT, NOUT_PAD, Wcth, Wctl);

  // layer 1
  k_agg1<<<(NNODES + 3) / 4, 256, 0, stream>>>(xh, rowstart, csr, dinv,
                                               (unsigned int*)aggx_hi, (unsigned int*)aggx_lo);
  {
    dim3 grid((NNODES + 127) / 128, HID / 128);
    k_mgemm<1, 1><<<grid, 256, 0, stream>>>(aggx_hi, aggx_lo, W1th, W1tl, b1,
                                            (void*)h1, nullptr, NNODES, HID, F_IN);
  }
  // layer 2
  k_agg2<<<(NNODES + 3) / 4, 256, 0, stream>>>(h1, rowstart, csr, dinv,
                                               (uint2*)aggh_hi, (uint2*)aggh_lo);
  {
    dim3 grid((NNODES + 127) / 128, HID / 128);
    k_mgemm<1, 2><<<grid, 256, 0, stream>>>(aggh_hi, aggh_lo, W2th, W2tl, b2,
                                            (void*)h2_hi, (void*)h2_lo, NNODES, HID, HID);
  }
  // classifier
  {
    dim3 grid((NNODES + 127) / 128, NOUT_PAD / 128);
    k_mgemm<0, 0><<<grid, 256, 0, stream>>>(h2_hi, h2_lo, Wcth, Wctl, bc,
                                            (void*)out, nullptr, NNODES, NOUT, HID);
  }
}

// Round 5
// 366.202 us; speedup vs baseline: 1.7524x; 1.0779x over previous
//
#include <hip/hip_runtime.h>

#define NNODES 50000
#define NEDGES 800000
#define F_IN   128
#define HID    256
#define NOUT   40
#define NOUT_PAD 128
#define NBLK_SCAN ((NNODES + 255) / 256)  // 196

typedef __attribute__((ext_vector_type(8))) _Float16 f16x8;
typedef __attribute__((ext_vector_type(4))) float f32x4;

__device__ __forceinline__ unsigned short f2h(float f) {
  return __builtin_bit_cast(unsigned short, (_Float16)f);
}
__device__ __forceinline__ float h2f(unsigned short u) {
  return (float)__builtin_bit_cast(_Float16, u);
}

// ---------------- CSR build ----------------

__global__ __launch_bounds__(256) void k_degree(const int* __restrict__ dst,
                                                int* __restrict__ count) {
  int e = blockIdx.x * 256 + threadIdx.x;
  if (e < NEDGES) atomicAdd(&count[dst[e]], 1);
}

__global__ __launch_bounds__(256) void k_scan1(const int* __restrict__ count,
                                               int* __restrict__ rowstart,
                                               int* __restrict__ bsum,
                                               float* __restrict__ dinv) {
  __shared__ int tmp[256];
  int t = threadIdx.x;
  int i = blockIdx.x * 256 + t;
  int v = (i < NNODES) ? count[i] : 0;
  if (i < NNODES) dinv[i] = rsqrtf((float)(v + 1));  // +1 self-loop
  tmp[t] = v;
  __syncthreads();
  for (int off = 1; off < 256; off <<= 1) {
    int x = (t >= off) ? tmp[t - off] : 0;
    __syncthreads();
    tmp[t] += x;
    __syncthreads();
  }
  if (i < NNODES) rowstart[i] = tmp[t] - v;  // exclusive
  if (t == 255) bsum[blockIdx.x] = tmp[255];
}

__global__ __launch_bounds__(256) void k_scan2(const int* __restrict__ bsum,
                                               int* __restrict__ boff) {
  __shared__ int tmp[256];
  int t = threadIdx.x;
  int v = (t < NBLK_SCAN) ? bsum[t] : 0;
  tmp[t] = v;
  __syncthreads();
  for (int off = 1; off < 256; off <<= 1) {
    int x = (t >= off) ? tmp[t - off] : 0;
    __syncthreads();
    tmp[t] += x;
    __syncthreads();
  }
  if (t < NBLK_SCAN) boff[t] = tmp[t] - v;  // exclusive
}

__global__ __launch_bounds__(256) void k_scan3(int* __restrict__ rowstart,
                                               const int* __restrict__ boff) {
  int i = blockIdx.x * 256 + threadIdx.x;
  if (i < NNODES) rowstart[i] += boff[blockIdx.x];
  if (i == 0) rowstart[NNODES] = NEDGES;
}

__global__ __launch_bounds__(256) void k_scatter(const int* __restrict__ src,
                                                 const int* __restrict__ dst,
                                                 const int* __restrict__ rowstart,
                                                 int* __restrict__ cursor,
                                                 int* __restrict__ csr) {
  int e = blockIdx.x * 256 + threadIdx.x;
  if (e >= NEDGES) return;
  int d = dst[e];
  int p = rowstart[d] + atomicAdd(&cursor[d], 1);
  csr[p] = src[e];
}

// ---------------- x -> fp16 cast ----------------

__global__ __launch_bounds__(256) void k_cast(const float* __restrict__ X,
                                              unsigned short* __restrict__ Xh) {
  int i = blockIdx.x * 256 + threadIdx.x;  // one float4 per thread
  if (i * 4 >= NNODES * F_IN) return;
  float4 v = *reinterpret_cast<const float4*>(X + (size_t)i * 4);
  ushort4 o;
  o.x = f2h(v.x); o.y = f2h(v.y); o.z = f2h(v.z); o.w = f2h(v.w);
  *reinterpret_cast<ushort4*>(Xh + (size_t)i * 4) = o;
}

// ---------------- weight transpose to fp16 ----------------
// T is [Npad][K] row-major = W^T; rows >= Nvalid zero-filled.

__global__ __launch_bounds__(256) void k_prep(const float* __restrict__ W, int K, int N,
                                              int Nvalid, int Npad,
                                              unsigned short* __restrict__ T) {
  int idx = blockIdx.x * 256 + threadIdx.x;
  if (idx >= Npad * K) return;
  int n = idx / K, k = idx - n * K;
  float v = (n < Nvalid) ? W[(size_t)k * N + n] : 0.f;
  T[idx] = f2h(v);
}

// ---------------- agg layer 1: fp16 gather (F=128), fp16 out -------
// Y[i] = dinv[i]^2 * X[i] + sum_{s->i} dinv[s]*dinv[i]*X[s]

__global__ __launch_bounds__(256) void k_agg1(const unsigned short* __restrict__ X,
                                              const int* __restrict__ rowstart,
                                              const int* __restrict__ csr,
                                              const float* __restrict__ dinv,
                                              unsigned int* __restrict__ Y) {
  int wave = threadIdx.x >> 6, lane = threadIdx.x & 63;
  int node = blockIdx.x * 4 + wave;
  if (node >= NNODES) return;
  float di = dinv[node];
  float a0, a1;
  {
    ushort2 v = *reinterpret_cast<const ushort2*>(X + (size_t)node * F_IN + lane * 2);
    a0 = h2f(v.x) * di * di; a1 = h2f(v.y) * di * di;
  }
  int e = rowstart[node], end = rowstart[node + 1];
  for (; e + 4 <= end; e += 4) {
    int s0 = csr[e], s1 = csr[e + 1], s2 = csr[e + 2], s3 = csr[e + 3];
    float w0 = dinv[s0] * di, w1 = dinv[s1] * di;
    float w2 = dinv[s2] * di, w3 = dinv[s3] * di;
    ushort2 r0 = *reinterpret_cast<const ushort2*>(X + (size_t)s0 * F_IN + lane * 2);
    ushort2 r1 = *reinterpret_cast<const ushort2*>(X + (size_t)s1 * F_IN + lane * 2);
    ushort2 r2 = *reinterpret_cast<const ushort2*>(X + (size_t)s2 * F_IN + lane * 2);
    ushort2 r3 = *reinterpret_cast<const ushort2*>(X + (size_t)s3 * F_IN + lane * 2);
    a0 = fmaf(h2f(r0.x), w0, a0); a1 = fmaf(h2f(r0.y), w0, a1);
    a0 = fmaf(h2f(r1.x), w1, a0); a1 = fmaf(h2f(r1.y), w1, a1);
    a0 = fmaf(h2f(r2.x), w2, a0); a1 = fmaf(h2f(r2.y), w2, a1);
    a0 = fmaf(h2f(r3.x), w3, a0); a1 = fmaf(h2f(r3.y), w3, a1);
  }
  for (; e < end; ++e) {
    int s = csr[e];
    float w = dinv[s] * di;
    ushort2 r = *reinterpret_cast<const ushort2*>(X + (size_t)s * F_IN + lane * 2);
    a0 = fmaf(h2f(r.x), w, a0); a1 = fmaf(h2f(r.y), w, a1);
  }
  Y[(size_t)node * 64 + lane] = (unsigned)f2h(a0) | ((unsigned)f2h(a1) << 16);
}

// ---------------- agg layer 2: fp16 gather (F=256), fp16 out -------

__global__ __launch_bounds__(256) void k_agg2(const unsigned short* __restrict__ H,
                                              const int* __restrict__ rowstart,
                                              const int* __restrict__ csr,
                                              const float* __restrict__ dinv,
                                              uint2* __restrict__ Y) {
  int wave = threadIdx.x >> 6, lane = threadIdx.x & 63;
  int node = blockIdx.x * 4 + wave;
  if (node >= NNODES) return;
  float di = dinv[node];
  float a0, a1, a2, a3;
  {
    ushort4 v = *reinterpret_cast<const ushort4*>(H + (size_t)node * HID + lane * 4);
    a0 = h2f(v.x) * di * di; a1 = h2f(v.y) * di * di;
    a2 = h2f(v.z) * di * di; a3 = h2f(v.w) * di * di;
  }
  int e = rowstart[node], end = rowstart[node + 1];
  for (; e + 4 <= end; e += 4) {
    int s0 = csr[e], s1 = csr[e + 1], s2 = csr[e + 2], s3 = csr[e + 3];
    float w0 = dinv[s0] * di, w1 = dinv[s1] * di;
    float w2 = dinv[s2] * di, w3 = dinv[s3] * di;
    ushort4 r0 = *reinterpret_cast<const ushort4*>(H + (size_t)s0 * HID + lane * 4);
    ushort4 r1 = *reinterpret_cast<const ushort4*>(H + (size_t)s1 * HID + lane * 4);
    ushort4 r2 = *reinterpret_cast<const ushort4*>(H + (size_t)s2 * HID + lane * 4);
    ushort4 r3 = *reinterpret_cast<const ushort4*>(H + (size_t)s3 * HID + lane * 4);
    a0 = fmaf(h2f(r0.x), w0, a0); a1 = fmaf(h2f(r0.y), w0, a1);
    a2 = fmaf(h2f(r0.z), w0, a2); a3 = fmaf(h2f(r0.w), w0, a3);
    a0 = fmaf(h2f(r1.x), w1, a0); a1 = fmaf(h2f(r1.y), w1, a1);
    a2 = fmaf(h2f(r1.z), w1, a2); a3 = fmaf(h2f(r1.w), w1, a3);
    a0 = fmaf(h2f(r2.x), w2, a0); a1 = fmaf(h2f(r2.y), w2, a1);
    a2 = fmaf(h2f(r2.z), w2, a2); a3 = fmaf(h2f(r2.w), w2, a3);
    a0 = fmaf(h2f(r3.x), w3, a0); a1 = fmaf(h2f(r3.y), w3, a1);
    a2 = fmaf(h2f(r3.z), w3, a2); a3 = fmaf(h2f(r3.w), w3, a3);
  }
  for (; e < end; ++e) {
    int s = csr[e];
    float w = dinv[s] * di;
    ushort4 r = *reinterpret_cast<const ushort4*>(H + (size_t)s * HID + lane * 4);
    a0 = fmaf(h2f(r.x), w, a0); a1 = fmaf(h2f(r.y), w, a1);
    a2 = fmaf(h2f(r.z), w, a2); a3 = fmaf(h2f(r.w), w, a3);
  }
  uint2 o;
  o.x = (unsigned)f2h(a0) | ((unsigned)f2h(a1) << 16);
  o.y = (unsigned)f2h(a2) | ((unsigned)f2h(a3) << 16);
  Y[(size_t)node * 64 + lane] = o;
}

// ---------------- fp16 MFMA GEMM ----------------
// C = A[MxK] @ B[KxN] + bias. A fp16 row-major [M][K]; B fp16 TRANSPOSED [Npad][K].
// BM=BN=128, BK=32, 4 waves (2x2), 64x64 out per wave. LDS rows padded to 40
// shorts (80 B). OMODE: 0 = f32 out, 1 = fp16 out.

template <int RELU, int OMODE>
__global__ __launch_bounds__(256) void k_mgemm(const unsigned short* __restrict__ Ag,
                                               const unsigned short* __restrict__ Btg,
                                               const float* __restrict__ bias,
                                               void* __restrict__ Cout,
                                               int M, int Nc, int K) {
  __shared__ unsigned short Ah[128 * 40], Bh[128 * 40];
  int tid = threadIdx.x;
  int lane = tid & 63, w = tid >> 6;
  int wr = w >> 1, wc = w & 1;
  int bm = blockIdx.x * 128, bn = blockIdx.y * 128;
  int l15 = lane & 15, kg = lane >> 4;

  f32x4 zero = {0.f, 0.f, 0.f, 0.f};
  f32x4 acc[4][4];
#pragma unroll
  for (int i = 0; i < 4; i++)
#pragma unroll
    for (int j = 0; j < 4; j++) acc[i][j] = zero;

  for (int kt = 0; kt < K; kt += 32) {
#pragma unroll
    for (int it = 0; it < 2; it++) {
      int c = tid + it * 256;
      int row = c >> 2, kq = c & 3;
      int ldso = row * 40 + kq * 8;
      {
        int gm = bm + row;
        uint4 v = {0, 0, 0, 0};
        if (gm < M) v = *reinterpret_cast<const uint4*>(Ag + (size_t)gm * K + kt + kq * 8);
        *reinterpret_cast<uint4*>(&Ah[ldso]) = v;
      }
      {
        size_t g = (size_t)(bn + row) * K + kt + kq * 8;
        *reinterpret_cast<uint4*>(&Bh[ldso]) = *reinterpret_cast<const uint4*>(Btg + g);
      }
    }
    __syncthreads();

    f16x8 fa[4], fb[4];
#pragma unroll
    for (int f = 0; f < 4; f++) {
      int ra = (wr * 64 + f * 16 + l15) * 40 + kg * 8;
      fa[f] = *reinterpret_cast<const f16x8*>(&Ah[ra]);
      int rb = (wc * 64 + f * 16 + l15) * 40 + kg * 8;
      fb[f] = *reinterpret_cast<const f16x8*>(&Bh[rb]);
    }
#pragma unroll
    for (int i = 0; i < 4; i++)
#pragma unroll
      for (int j = 0; j < 4; j++)
        acc[i][j] = __builtin_amdgcn_mfma_f32_16x16x32_f16(fa[i], fb[j], acc[i][j], 0, 0, 0);
    __syncthreads();
  }

  // epilogue: D col = lane&15, row(frag) = (lane>>4)*4 + reg
  int r0 = kg * 4;
#pragma unroll
  for (int i = 0; i < 4; i++) {
    int gmBase = bm + wr * 64 + i * 16 + r0;
#pragma unroll
    for (int r = 0; r < 4; r++) {
      int gm = gmBase + r;
      if (gm >= M) continue;
#pragma unroll
      for (int j = 0; j < 4; j++) {
        int gn = bn + wc * 64 + j * 16 + l15;
        if (gn >= Nc) continue;
        float v = acc[i][j][r] + bias[gn];
        if (RELU) v = fmaxf(v, 0.f);
        size_t o = (size_t)gm * Nc + gn;
        if (OMODE == 0) ((float*)Cout)[o] = v;
        else            ((unsigned short*)Cout)[o] = f2h(v);
      }
    }
  }
}

// ---------------- launch ----------------

extern "C" void kernel_launch(void* const* d_in, const int* in_sizes, int n_in,
                              void* d_out, int out_size, void* d_ws, size_t ws_size,
                              hipStream_t stream) {
  (void)in_sizes; (void)n_in; (void)out_size; (void)ws_size;
  const float* x  = (const float*)d_in[0];
  const float* W1 = (const float*)d_in[1];
  const float* b1 = (const float*)d_in[2];
  const float* W2 = (const float*)d_in[3];
  const float* b2 = (const float*)d_in[4];
  const float* Wc = (const float*)d_in[5];
  const float* bc = (const float*)d_in[6];
  const int* edge = (const int*)d_in[7];
  const int* srcE = edge;
  const int* dstE = edge + NEDGES;
  float* out = (float*)d_out;

  char* ws = (char*)d_ws;
  int*   count    = (int*)(ws + 0);          // 200000 B
  int*   cursor   = (int*)(ws + 200064);
  int*   rowstart = (int*)(ws + 400128);     // 200004 B
  float* dinv     = (float*)(ws + 600320);
  int*   csr      = (int*)(ws + 800384);     // 3.2 MB -> ends 4000384
  int*   bsum     = (int*)(ws + 4000512);
  int*   boff     = (int*)(ws + 4001536);
  unsigned short* W1t = (unsigned short*)(ws + 4002560);   // 256x128 fp16 (64 KB)
  unsigned short* W2t = (unsigned short*)(ws + 4068096);   // 256x256 fp16 (128 KB)
  unsigned short* Wct = (unsigned short*)(ws + 4199168);   // 128x256 fp16 (64 KB, padded)
  unsigned short* xh  = (unsigned short*)(ws + 4264704);   // 50000x128 fp16 (12.8 MB)
  unsigned short* aggx = (unsigned short*)(ws + 17064704); // 50000x128 fp16
  unsigned short* h1   = (unsigned short*)(ws + 29864704); // 50000x256 fp16 (25.6 MB)
  unsigned short* aggh = (unsigned short*)(ws + 55464704); // 50000x256 fp16
  unsigned short* h2   = (unsigned short*)(ws + 81064704); // 50000x256 fp16  (ends ~107 MB)

  hipMemsetAsync(ws, 0, 400128, stream);  // count + cursor

  k_cast<<<(NNODES * F_IN / 4 + 255) / 256, 256, 0, stream>>>(x, xh);
  k_degree<<<(NEDGES + 255) / 256, 256, 0, stream>>>(dstE, count);
  k_scan1<<<NBLK_SCAN, 256, 0, stream>>>(count, rowstart, bsum, dinv);
  k_scan2<<<1, 256, 0, stream>>>(bsum, boff);
  k_scan3<<<NBLK_SCAN, 256, 0, stream>>>(rowstart, boff);
  k_scatter<<<(NEDGES + 255) / 256, 256, 0, stream>>>(srcE, dstE, rowstart, cursor, csr);

  k_prep<<<(HID * F_IN + 255) / 256, 256, 0, stream>>>(W1, F_IN, HID, HID, HID, W1t);
  k_prep<<<(HID * HID + 255) / 256, 256, 0, stream>>>(W2, HID, HID, HID, HID, W2t);
  k_prep<<<(NOUT_PAD * HID + 255) / 256, 256, 0, stream>>>(Wc, HID, NOUT, NOUT, NOUT_PAD, Wct);

  // layer 1
  k_agg1<<<(NNODES + 3) / 4, 256, 0, stream>>>(xh, rowstart, csr, dinv, (unsigned int*)aggx);
  {
    dim3 grid((NNODES + 127) / 128, HID / 128);
    k_mgemm<1, 1><<<grid, 256, 0, stream>>>(aggx, W1t, b1, (void*)h1, NNODES, HID, F_IN);
  }
  // layer 2
  k_agg2<<<(NNODES + 3) / 4, 256, 0, stream>>>(h1, rowstart, csr, dinv, (uint2*)aggh);
  {
    dim3 grid((NNODES + 127) / 128, HID / 128);
    k_mgemm<1, 1><<<grid, 256, 0, stream>>>(aggh, W2t, b2, (void*)h2, NNODES, HID, HID);
  }
  // classifier
  {
    dim3 grid((NNODES + 127) / 128, NOUT_PAD / 128);
    k_mgemm<0, 0><<<grid, 256, 0, stream>>>(h2, Wct, bc, (void*)out, NNODES, NOUT, HID);
  }
}

// Round 6
// 351.713 us; speedup vs baseline: 1.8246x; 1.0412x over previous
//
#include <hip/hip_runtime.h>

#define NNODES 50000
#define NEDGES 800000
#define F_IN   128
#define HID    256
#define NOUT   40
#define NOUT_PAD 48
#define NBLK_SCAN ((NNODES + 255) / 256)  // 196
#define NBLK_CAST 6250                     // 50000*128/4/256
#define NBLK_DEG  3125                     // 800000/256

typedef __attribute__((ext_vector_type(8))) _Float16 f16x8;
typedef __attribute__((ext_vector_type(4))) float f32x4;
typedef __attribute__((ext_vector_type(4))) unsigned short u16x4;
typedef __attribute__((ext_vector_type(8))) unsigned short u16x8;

__device__ __forceinline__ unsigned short f2h(float f) {
  return __builtin_bit_cast(unsigned short, (_Float16)f);
}
__device__ __forceinline__ float h2f(unsigned short u) {
  return (float)__builtin_bit_cast(_Float16, u);
}

// ---------------- fused x->fp16 cast + degree histogram ----------------

__global__ __launch_bounds__(256) void k_pre(const float* __restrict__ X,
                                             unsigned short* __restrict__ Xh,
                                             const int* __restrict__ dst,
                                             int* __restrict__ count) {
  if (blockIdx.x < NBLK_CAST) {
    int i = blockIdx.x * 256 + threadIdx.x;
    float4 v = *reinterpret_cast<const float4*>(X + (size_t)i * 4);
    ushort4 o;
    o.x = f2h(v.x); o.y = f2h(v.y); o.z = f2h(v.z); o.w = f2h(v.w);
    *reinterpret_cast<ushort4*>(Xh + (size_t)i * 4) = o;
  } else {
    int e = (blockIdx.x - NBLK_CAST) * 256 + threadIdx.x;
    if (e < NEDGES) atomicAdd(&count[dst[e]], 1);
  }
}

// ---------------- CSR build ----------------

__global__ __launch_bounds__(256) void k_scan1(const int* __restrict__ count,
                                               int* __restrict__ rowstart,
                                               int* __restrict__ bsum,
                                               float* __restrict__ dinv) {
  __shared__ int tmp[256];
  int t = threadIdx.x;
  int i = blockIdx.x * 256 + t;
  int v = (i < NNODES) ? count[i] : 0;
  if (i < NNODES) dinv[i] = rsqrtf((float)(v + 1));  // +1 self-loop
  tmp[t] = v;
  __syncthreads();
  for (int off = 1; off < 256; off <<= 1) {
    int x = (t >= off) ? tmp[t - off] : 0;
    __syncthreads();
    tmp[t] += x;
    __syncthreads();
  }
  if (i < NNODES) rowstart[i] = tmp[t] - v;  // exclusive
  if (t == 255) bsum[blockIdx.x] = tmp[255];
}

__global__ __launch_bounds__(256) void k_scan2(const int* __restrict__ bsum,
                                               int* __restrict__ boff) {
  __shared__ int tmp[256];
  int t = threadIdx.x;
  int v = (t < NBLK_SCAN) ? bsum[t] : 0;
  tmp[t] = v;
  __syncthreads();
  for (int off = 1; off < 256; off <<= 1) {
    int x = (t >= off) ? tmp[t - off] : 0;
    __syncthreads();
    tmp[t] += x;
    __syncthreads();
  }
  if (t < NBLK_SCAN) boff[t] = tmp[t] - v;  // exclusive
}

__global__ __launch_bounds__(256) void k_scan3(int* __restrict__ rowstart,
                                               const int* __restrict__ boff) {
  int i = blockIdx.x * 256 + threadIdx.x;
  if (i < NNODES) rowstart[i] += boff[blockIdx.x];
  if (i == 0) rowstart[NNODES] = NEDGES;
}

__global__ __launch_bounds__(256) void k_scatter(const int* __restrict__ src,
                                                 const int* __restrict__ dst,
                                                 const int* __restrict__ rowstart,
                                                 int* __restrict__ cursor,
                                                 int* __restrict__ csr) {
  int e = blockIdx.x * 256 + threadIdx.x;
  if (e >= NEDGES) return;
  int d = dst[e];
  int p = rowstart[d] + atomicAdd(&cursor[d], 1);
  csr[p] = src[e];
}

// ---------------- fused weight transpose to fp16 (all three) ----------------
// T layouts: [Npad][K] row-major = W^T.

__global__ __launch_bounds__(256) void k_prep3(const float* __restrict__ W1,
                                               const float* __restrict__ W2,
                                               const float* __restrict__ Wc,
                                               unsigned short* __restrict__ T1,
                                               unsigned short* __restrict__ T2,
                                               unsigned short* __restrict__ Tc) {
  int b = blockIdx.x;
  if (b < 128) {                      // W1: [128][256] -> T1 [256][128]
    int idx = b * 256 + threadIdx.x;  // 32768 total
    int n = idx >> 7, k = idx & 127;
    T1[idx] = f2h(W1[(size_t)k * HID + n]);
  } else if (b < 384) {               // W2: [256][256] -> T2 [256][256]
    int idx = (b - 128) * 256 + threadIdx.x;  // 65536 total
    int n = idx >> 8, k = idx & 255;
    T2[idx] = f2h(W2[(size_t)k * HID + n]);
  } else {                            // Wc: [256][40] -> Tc [48][256], zero-pad
    int idx = (b - 384) * 256 + threadIdx.x;  // 12288 total
    int n = idx >> 8, k = idx & 255;
    float v = (n < NOUT) ? Wc[(size_t)k * NOUT + n] : 0.f;
    Tc[idx] = f2h(v);
  }
}

// ---------------- agg layer 1: half-wave fp16 gather (F=128) ----------------
// lanes 0-31 gather edge e, lanes 32-63 edge e+1; 8B/lane; shfl reduce.

__global__ __launch_bounds__(256) void k_agg1(const unsigned short* __restrict__ X,
                                              const int* __restrict__ rowstart,
                                              const int* __restrict__ csr,
                                              const float* __restrict__ dinv,
                                              uint2* __restrict__ Y) {
  int wave = threadIdx.x >> 6, lane = threadIdx.x & 63;
  int node = blockIdx.x * 4 + wave;
  if (node >= NNODES) return;
  int half = lane >> 5, l32 = lane & 31;
  float di = dinv[node];
  float a[4] = {0.f, 0.f, 0.f, 0.f};
  int e = rowstart[node], end = rowstart[node + 1];
  for (; e + 8 <= end; e += 8) {
    int s0 = csr[e + 0 + half], s1 = csr[e + 2 + half];
    int s2 = csr[e + 4 + half], s3 = csr[e + 6 + half];
    float w0 = dinv[s0] * di, w1 = dinv[s1] * di;
    float w2 = dinv[s2] * di, w3 = dinv[s3] * di;
    u16x4 r0 = *reinterpret_cast<const u16x4*>(X + (size_t)s0 * F_IN + l32 * 4);
    u16x4 r1 = *reinterpret_cast<const u16x4*>(X + (size_t)s1 * F_IN + l32 * 4);
    u16x4 r2 = *reinterpret_cast<const u16x4*>(X + (size_t)s2 * F_IN + l32 * 4);
    u16x4 r3 = *reinterpret_cast<const u16x4*>(X + (size_t)s3 * F_IN + l32 * 4);
#pragma unroll
    for (int k = 0; k < 4; k++) {
      a[k] = fmaf(h2f(r0[k]), w0, a[k]);
      a[k] = fmaf(h2f(r1[k]), w1, a[k]);
      a[k] = fmaf(h2f(r2[k]), w2, a[k]);
      a[k] = fmaf(h2f(r3[k]), w3, a[k]);
    }
  }
  for (; e + 2 <= end; e += 2) {
    int s = csr[e + half];
    float w = dinv[s] * di;
    u16x4 r = *reinterpret_cast<const u16x4*>(X + (size_t)s * F_IN + l32 * 4);
#pragma unroll
    for (int k = 0; k < 4; k++) a[k] = fmaf(h2f(r[k]), w, a[k]);
  }
  if (e < end) {  // odd remainder: both halves read it, half 1 weight 0
    int s = csr[e];
    float w = half ? 0.f : dinv[s] * di;
    u16x4 r = *reinterpret_cast<const u16x4*>(X + (size_t)s * F_IN + l32 * 4);
#pragma unroll
    for (int k = 0; k < 4; k++) a[k] = fmaf(h2f(r[k]), w, a[k]);
  }
#pragma unroll
  for (int k = 0; k < 4; k++) a[k] += __shfl_xor(a[k], 32);
  if (half == 0) {
    u16x4 self = *reinterpret_cast<const u16x4*>(X + (size_t)node * F_IN + l32 * 4);
    float dd = di * di;
#pragma unroll
    for (int k = 0; k < 4; k++) a[k] = fmaf(h2f(self[k]), dd, a[k]);
    uint2 o;
    o.x = (unsigned)f2h(a[0]) | ((unsigned)f2h(a[1]) << 16);
    o.y = (unsigned)f2h(a[2]) | ((unsigned)f2h(a[3]) << 16);
    Y[(size_t)node * 32 + l32] = o;
  }
}

// ---------------- agg layer 2: half-wave fp16 gather (F=256) ----------------

__global__ __launch_bounds__(256) void k_agg2(const unsigned short* __restrict__ H,
                                              const int* __restrict__ rowstart,
                                              const int* __restrict__ csr,
                                              const float* __restrict__ dinv,
                                              uint4* __restrict__ Y) {
  int wave = threadIdx.x >> 6, lane = threadIdx.x & 63;
  int node = blockIdx.x * 4 + wave;
  if (node >= NNODES) return;
  int half = lane >> 5, l32 = lane & 31;
  float di = dinv[node];
  float a[8] = {0.f, 0.f, 0.f, 0.f, 0.f, 0.f, 0.f, 0.f};
  int e = rowstart[node], end = rowstart[node + 1];
  for (; e + 8 <= end; e += 8) {
    int s0 = csr[e + 0 + half], s1 = csr[e + 2 + half];
    int s2 = csr[e + 4 + half], s3 = csr[e + 6 + half];
    float w0 = dinv[s0] * di, w1 = dinv[s1] * di;
    float w2 = dinv[s2] * di, w3 = dinv[s3] * di;
    u16x8 r0 = *reinterpret_cast<const u16x8*>(H + (size_t)s0 * HID + l32 * 8);
    u16x8 r1 = *reinterpret_cast<const u16x8*>(H + (size_t)s1 * HID + l32 * 8);
    u16x8 r2 = *reinterpret_cast<const u16x8*>(H + (size_t)s2 * HID + l32 * 8);
    u16x8 r3 = *reinterpret_cast<const u16x8*>(H + (size_t)s3 * HID + l32 * 8);
#pragma unroll
    for (int k = 0; k < 8; k++) {
      a[k] = fmaf(h2f(r0[k]), w0, a[k]);
      a[k] = fmaf(h2f(r1[k]), w1, a[k]);
      a[k] = fmaf(h2f(r2[k]), w2, a[k]);
      a[k] = fmaf(h2f(r3[k]), w3, a[k]);
    }
  }
  for (; e + 2 <= end; e += 2) {
    int s = csr[e + half];
    float w = dinv[s] * di;
    u16x8 r = *reinterpret_cast<const u16x8*>(H + (size_t)s * HID + l32 * 8);
#pragma unroll
    for (int k = 0; k < 8; k++) a[k] = fmaf(h2f(r[k]), w, a[k]);
  }
  if (e < end) {
    int s = csr[e];
    float w = half ? 0.f : dinv[s] * di;
    u16x8 r = *reinterpret_cast<const u16x8*>(H + (size_t)s * HID + l32 * 8);
#pragma unroll
    for (int k = 0; k < 8; k++) a[k] = fmaf(h2f(r[k]), w, a[k]);
  }
#pragma unroll
  for (int k = 0; k < 8; k++) a[k] += __shfl_xor(a[k], 32);
  if (half == 0) {
    u16x8 self = *reinterpret_cast<const u16x8*>(H + (size_t)node * HID + l32 * 8);
    float dd = di * di;
#pragma unroll
    for (int k = 0; k < 8; k++) a[k] = fmaf(h2f(self[k]), dd, a[k]);
    uint4 o;
    o.x = (unsigned)f2h(a[0]) | ((unsigned)f2h(a[1]) << 16);
    o.y = (unsigned)f2h(a[2]) | ((unsigned)f2h(a[3]) << 16);
    o.z = (unsigned)f2h(a[4]) | ((unsigned)f2h(a[5]) << 16);
    o.w = (unsigned)f2h(a[6]) | ((unsigned)f2h(a[7]) << 16);
    Y[(size_t)node * 32 + l32] = o;
  }
}

// ---------------- fp16 MFMA GEMM, double-buffered, 1 barrier/K-step --------
// C = A[MxK] @ B[KxN] + bias. A fp16 [M][K]; B fp16 transposed [Npad][K].
// BM=BN=128, BK=32, 4 waves (2x2). OMODE: 0 = f32 out, 1 = fp16 out.

template <int RELU, int OMODE>
__global__ __launch_bounds__(256) void k_mgemm(const unsigned short* __restrict__ Ag,
                                               const unsigned short* __restrict__ Btg,
                                               const float* __restrict__ bias,
                                               void* __restrict__ Cout,
                                               int M, int Nc, int K) {
  __shared__ unsigned short Ah[2][128 * 40];
  __shared__ unsigned short Bh[2][128 * 40];
  int tid = threadIdx.x;
  int lane = tid & 63, w = tid >> 6;
  int wr = w >> 1, wc = w & 1;
  int bm = blockIdx.x * 128, bn = blockIdx.y * 128;
  int l15 = lane & 15, kg = lane >> 4;
  int row0 = tid >> 2, kq0 = (tid & 3) * 8;  // this thread stages rows {row0,row0+64}
  int gm0 = bm + row0, gm1 = bm + row0 + 64;

  f32x4 zero = {0.f, 0.f, 0.f, 0.f};
  f32x4 acc[4][4];
#pragma unroll
  for (int i = 0; i < 4; i++)
#pragma unroll
    for (int j = 0; j < 4; j++) acc[i][j] = zero;

  uint4 ra0, ra1, rb0, rb1;
  const uint4 z4 = {0, 0, 0, 0};
#define LOADT(KT)                                                                    \
  {                                                                                  \
    ra0 = z4; ra1 = z4;                                                              \
    if (gm0 < M) ra0 = *reinterpret_cast<const uint4*>(Ag + (size_t)gm0 * K + (KT) + kq0); \
    if (gm1 < M) ra1 = *reinterpret_cast<const uint4*>(Ag + (size_t)gm1 * K + (KT) + kq0); \
    rb0 = *reinterpret_cast<const uint4*>(Btg + (size_t)(bn + row0) * K + (KT) + kq0);     \
    rb1 = *reinterpret_cast<const uint4*>(Btg + (size_t)(bn + row0 + 64) * K + (KT) + kq0);\
  }
#define STORET(B)                                                       \
  {                                                                     \
    *reinterpret_cast<uint4*>(&Ah[B][row0 * 40 + kq0]) = ra0;           \
    *reinterpret_cast<uint4*>(&Ah[B][(row0 + 64) * 40 + kq0]) = ra1;    \
    *reinterpret_cast<uint4*>(&Bh[B][row0 * 40 + kq0]) = rb0;           \
    *reinterpret_cast<uint4*>(&Bh[B][(row0 + 64) * 40 + kq0]) = rb1;    \
  }

  LOADT(0);
  STORET(0);
  __syncthreads();
  int nt = K >> 5, cur = 0;
  for (int t = 0; t < nt; t++) {
    bool pf = (t + 1 < nt);
    if (pf) LOADT((t + 1) << 5);  // in flight over ds_read + MFMA
    f16x8 fa[4], fb[4];
#pragma unroll
    for (int f = 0; f < 4; f++) {
      fa[f] = *reinterpret_cast<const f16x8*>(&Ah[cur][(wr * 64 + f * 16 + l15) * 40 + kg * 8]);
      fb[f] = *reinterpret_cast<const f16x8*>(&Bh[cur][(wc * 64 + f * 16 + l15) * 40 + kg * 8]);
    }
#pragma unroll
    for (int i = 0; i < 4; i++)
#pragma unroll
      for (int j = 0; j < 4; j++)
        acc[i][j] = __builtin_amdgcn_mfma_f32_16x16x32_f16(fa[i], fb[j], acc[i][j], 0, 0, 0);
    if (pf) STORET(cur ^ 1);  // different buffer than anyone's reads
    __syncthreads();
    cur ^= 1;
  }
#undef LOADT
#undef STORET

  int r0 = kg * 4;
#pragma unroll
  for (int i = 0; i < 4; i++) {
    int gmBase = bm + wr * 64 + i * 16 + r0;
#pragma unroll
    for (int r = 0; r < 4; r++) {
      int gm = gmBase + r;
      if (gm >= M) continue;
#pragma unroll
      for (int j = 0; j < 4; j++) {
        int gn = bn + wc * 64 + j * 16 + l15;
        if (gn >= Nc) continue;
        float v = acc[i][j][r] + bias[gn];
        if (RELU) v = fmaxf(v, 0.f);
        size_t o = (size_t)gm * Nc + gn;
        if (OMODE == 0) ((float*)Cout)[o] = v;
        else            ((unsigned short*)Cout)[o] = f2h(v);
      }
    }
  }
}

// ---------------- classifier: BM=256, BN=48 (NOUT=40), fp32 out -------------
// 4 waves stacked over M; each wave 64 rows x 48 cols (4 m-frags x 3 n-frags).

__global__ __launch_bounds__(256) void k_cls(const unsigned short* __restrict__ Ag,
                                             const unsigned short* __restrict__ Btg,
                                             const float* __restrict__ bias,
                                             float* __restrict__ C, int M) {
  __shared__ unsigned short As[256 * 40];
  __shared__ unsigned short Bs[48 * 40];
  int tid = threadIdx.x;
  int lane = tid & 63, w = tid >> 6;
  int l15 = lane & 15, kg = lane >> 4;
  int bm = blockIdx.x * 256;

  f32x4 zero = {0.f, 0.f, 0.f, 0.f};
  f32x4 acc[4][3];
#pragma unroll
  for (int i = 0; i < 4; i++)
#pragma unroll
    for (int j = 0; j < 3; j++) acc[i][j] = zero;

  for (int kt = 0; kt < HID; kt += 32) {
#pragma unroll
    for (int it = 0; it < 4; it++) {  // A: 256 rows x 4 chunks
      int c = tid + it * 256;
      int row = c >> 2, kq = (c & 3) * 8;
      int gm = bm + row;
      uint4 v = {0, 0, 0, 0};
      if (gm < M) v = *reinterpret_cast<const uint4*>(Ag + (size_t)gm * HID + kt + kq);
      *reinterpret_cast<uint4*>(&As[row * 40 + kq]) = v;
    }
    if (tid < 192) {  // B: 48 rows x 4 chunks
      int row = tid >> 2, kq = (tid & 3) * 8;
      *reinterpret_cast<uint4*>(&Bs[row * 40 + kq]) =
          *reinterpret_cast<const uint4*>(Btg + (size_t)row * HID + kt + kq);
    }
    __syncthreads();
    f16x8 fa[4], fb[3];
#pragma unroll
    for (int f = 0; f < 4; f++)
      fa[f] = *reinterpret_cast<const f16x8*>(&As[(w * 64 + f * 16 + l15) * 40 + kg * 8]);
#pragma unroll
    for (int j = 0; j < 3; j++)
      fb[j] = *reinterpret_cast<const f16x8*>(&Bs[(j * 16 + l15) * 40 + kg * 8]);
#pragma unroll
    for (int i = 0; i < 4; i++)
#pragma unroll
      for (int j = 0; j < 3; j++)
        acc[i][j] = __builtin_amdgcn_mfma_f32_16x16x32_f16(fa[i], fb[j], acc[i][j], 0, 0, 0);
    __syncthreads();
  }

  int r0 = kg * 4;
#pragma unroll
  for (int i = 0; i < 4; i++) {
    int gmBase = bm + w * 64 + i * 16 + r0;
#pragma unroll
    for (int r = 0; r < 4; r++) {
      int gm = gmBase + r;
      if (gm >= M) continue;
#pragma unroll
      for (int j = 0; j < 3; j++) {
        int gn = j * 16 + l15;
        if (gn >= NOUT) continue;
        C[(size_t)gm * NOUT + gn] = acc[i][j][r] + bias[gn];
      }
    }
  }
}

// ---------------- launch ----------------

extern "C" void kernel_launch(void* const* d_in, const int* in_sizes, int n_in,
                              void* d_out, int out_size, void* d_ws, size_t ws_size,
                              hipStream_t stream) {
  (void)in_sizes; (void)n_in; (void)out_size; (void)ws_size;
  const float* x  = (const float*)d_in[0];
  const float* W1 = (const float*)d_in[1];
  const float* b1 = (const float*)d_in[2];
  const float* W2 = (const float*)d_in[3];
  const float* b2 = (const float*)d_in[4];
  const float* Wc = (const float*)d_in[5];
  const float* bc = (const float*)d_in[6];
  const int* edge = (const int*)d_in[7];
  const int* srcE = edge;
  const int* dstE = edge + NEDGES;
  float* out = (float*)d_out;

  char* ws = (char*)d_ws;
  int*   count    = (int*)(ws + 0);          // 200000 B
  int*   cursor   = (int*)(ws + 200064);
  int*   rowstart = (int*)(ws + 400128);     // 200004 B
  float* dinv     = (float*)(ws + 600320);
  int*   csr      = (int*)(ws + 800384);     // 3.2 MB
  int*   bsum     = (int*)(ws + 4000512);
  int*   boff     = (int*)(ws + 4001536);
  unsigned short* W1t = (unsigned short*)(ws + 4002560);   // 256x128 fp16
  unsigned short* W2t = (unsigned short*)(ws + 4068096);   // 256x256 fp16
  unsigned short* Wct = (unsigned short*)(ws + 4199168);   // 48x256 fp16
  unsigned short* xh  = (unsigned short*)(ws + 4264704);   // 50000x128 fp16
  unsigned short* aggx = (unsigned short*)(ws + 17064704); // 50000x128 fp16
  unsigned short* h1   = (unsigned short*)(ws + 29864704); // 50000x256 fp16
  unsigned short* aggh = (unsigned short*)(ws + 55464704); // 50000x256 fp16
  unsigned short* h2   = (unsigned short*)(ws + 81064704); // 50000x256 fp16

  hipMemsetAsync(ws, 0, 400128, stream);  // count + cursor

  k_pre<<<NBLK_CAST + NBLK_DEG, 256, 0, stream>>>(x, xh, dstE, count);
  k_scan1<<<NBLK_SCAN, 256, 0, stream>>>(count, rowstart, bsum, dinv);
  k_scan2<<<1, 256, 0, stream>>>(bsum, boff);
  k_scan3<<<NBLK_SCAN, 256, 0, stream>>>(rowstart, boff);
  k_scatter<<<(NEDGES + 255) / 256, 256, 0, stream>>>(srcE, dstE, rowstart, cursor, csr);
  k_prep3<<<432, 256, 0, stream>>>(W1, W2, Wc, W1t, W2t, Wct);

  // layer 1
  k_agg1<<<(NNODES + 3) / 4, 256, 0, stream>>>(xh, rowstart, csr, dinv, (uint2*)aggx);
  {
    dim3 grid((NNODES + 127) / 128, HID / 128);
    k_mgemm<1, 1><<<grid, 256, 0, stream>>>(aggx, W1t, b1, (void*)h1, NNODES, HID, F_IN);
  }
  // layer 2
  k_agg2<<<(NNODES + 3) / 4, 256, 0, stream>>>(h1, rowstart, csr, dinv, (uint4*)aggh);
  {
    dim3 grid((NNODES + 127) / 128, HID / 128);
    k_mgemm<1, 1><<<grid, 256, 0, stream>>>(aggh, W2t, b2, (void*)h2, NNODES, HID, HID);
  }
  // classifier (48-col tile, only 40 written)
  k_cls<<<(NNODES + 255) / 256, 256, 0, stream>>>(h2, Wct, bc, out, NNODES);
}